// Round 1
// baseline (14850.641 us; speedup 1.0000x reference)
//
#include <hip/hip_runtime.h>
#include <math.h>

#define EPSV 1e-5f

// ---------------- weight repack kernels (run once per launch) ----------------
// adapt_w [L][co][ci] -> wTa [L][ci][co]
__global__ __launch_bounds__(256) void k_repackT(const float* __restrict__ in, float* __restrict__ out){
  int idx = blockIdx.x*256 + threadIdx.x;
  if (idx >= 4*256*256) return;
  int co = idx & 255, ci = (idx>>8)&255, l = idx>>16;
  out[idx] = in[((size_t)(l*256+co)<<8) + ci];
}

// w [L][co][ci][9] -> wr [L][9][ci][co]
__global__ __launch_bounds__(256) void k_repack3(const float* __restrict__ in, float* __restrict__ out){
  int idx = blockIdx.x*256 + threadIdx.x;
  if (idx >= 4*9*256*256) return;
  int co = idx & 255;
  int r = idx >> 8;
  int ci = r & 255;
  r >>= 8;                 // r = l*9 + t
  int t = r % 9, l = r / 9;
  out[idx] = in[(size_t)((l*256+co)*256+ci)*9 + t];
}

// wp [L][o(45)][ci] -> wpT [L][ci][o]
__global__ __launch_bounds__(256) void k_repackP(const float* __restrict__ in, float* __restrict__ out){
  int idx = blockIdx.x*256 + threadIdx.x;
  if (idx >= 4*256*45) return;
  int o = idx % 45;
  int r = idx / 45;
  int ci = r & 255, l = r >> 8;
  out[idx] = in[(size_t)(l*45+o)*256 + ci];
}

// ---------------- adapt: 1x1 conv, feat (global, full image) -> buf0 chunk ----------------
__global__ __launch_bounds__(256) void k_adapt(
    const float* __restrict__ feat, const float* __restrict__ wT,
    const float* __restrict__ bias, float* __restrict__ out,
    int H, int W, int y_begin, int slot_begin, int RB0)
{
  __shared__ __align__(16) float Xs[16][64];
  __shared__ __align__(16) float Wsm[16][64];
  int tid = threadIdx.x;
  int tx = tid & 15, ty = tid >> 4;
  int nPxT = (W + 63) >> 6;
  int pxt = blockIdx.x % nPxT;
  int cot = blockIdx.x / nPxT;
  int x0 = pxt * 64, co0 = cot * 64;
  int y = y_begin + blockIdx.y;
  int b = blockIdx.z;
  int slot = slot_begin + blockIdx.y;
  bool full = (x0 + 64 <= W);
  const float* fb = feat + ((size_t)(b*256)*H + y) * W;
  float acc[4][4] = {};
  int sk = tid >> 4, sx = (tid & 15) * 4;
  for (int k0 = 0; k0 < 256; k0 += 16){
    float4 xv = make_float4(0.f,0.f,0.f,0.f);
    {
      const float* src = fb + (size_t)(k0+sk)*H*W + x0 + sx;
      if (full) xv = *(const float4*)src;
      else {
        float t4[4] = {0.f,0.f,0.f,0.f};
        int xg = x0 + sx;
        #pragma unroll
        for (int m=0;m<4;m++) if (xg+m < W) t4[m] = src[m];
        xv = make_float4(t4[0],t4[1],t4[2],t4[3]);
      }
    }
    float4 wv = *(const float4*)(wT + (size_t)(k0+sk)*256 + co0 + sx);
    *(float4*)&Xs[sk][sx] = xv;
    *(float4*)&Wsm[sk][sx] = wv;
    __syncthreads();
    #pragma unroll
    for (int k=0;k<16;k++){
      float4 av = *(const float4*)&Wsm[k][ty*4];
      float4 bv = *(const float4*)&Xs[k][tx*4];
      float aarr[4] = {av.x, av.y, av.z, av.w};
      float barr[4] = {bv.x, bv.y, bv.z, bv.w};
      #pragma unroll
      for (int i=0;i<4;i++)
        #pragma unroll
        for (int j=0;j<4;j++)
          acc[i][j] = fmaf(aarr[i], barr[j], acc[i][j]);
    }
    __syncthreads();
  }
  int xbase = x0 + tx*4;
  #pragma unroll
  for (int i=0;i<4;i++){
    int co = co0 + ty*4 + i;
    float bs = bias[co];
    float* dst = out + (((size_t)(b*256+co))*RB0 + slot)*W + xbase;
    if (full){
      float4 v = make_float4(acc[i][0]+bs, acc[i][1]+bs, acc[i][2]+bs, acc[i][3]+bs);
      *(float4*)dst = v;
    } else {
      #pragma unroll
      for (int j=0;j<4;j++) if (xbase+j < W) dst[j] = acc[i][j]+bs;
    }
  }
}

// ---------------- 3x3 conv + BN + ReLU, buffer -> buffer ----------------
__global__ __launch_bounds__(256) void k_conv3(
    const float* __restrict__ inb, const float* __restrict__ wr,
    const float* __restrict__ bias, const float* __restrict__ gam,
    const float* __restrict__ bet, const float* __restrict__ mu,
    const float* __restrict__ var, float* __restrict__ outb,
    int H, int W, int y_begin, int islot_base, int RBin,
    int oslot_begin, int RBout)
{
  __shared__ __align__(16) float Xs[16][3][68];   // 66 valid cols: x0-1 .. x0+64
  __shared__ __align__(16) float Wsm[16][9][64];
  int tid = threadIdx.x;
  int tx = tid & 15, ty = tid >> 4;
  int nPxT = (W + 63) >> 6;
  int pxt = blockIdx.x % nPxT, cot = blockIdx.x / nPxT;
  int x0 = pxt*64, co0 = cot*64;
  int y = y_begin + blockIdx.y;
  int b = blockIdx.z;
  bool full = (x0+64 <= W);
  float acc[4][4] = {};
  const float* inbb = inb + (size_t)(b*256)*RBin*W;

  for (int k0=0;k0<256;k0+=16){
    // stage X tile with halo (zero-padded at image borders)
    for (int idx=tid; idx<16*3*68; idx+=256){
      int k = idx / 204;
      int rr = idx % 204;
      int ky = rr / 68, xx = rr % 68;
      float v = 0.f;
      if (xx < 66){
        int xg = x0 - 1 + xx;
        int yg = y + ky - 1;
        if (xg >= 0 && xg < W && yg >= 0 && yg < H){
          int slot = islot_base + blockIdx.y + ky;
          v = inbb[((size_t)(k0+k)*RBin + slot)*W + xg];
        }
      }
      Xs[k][ky][xx] = v;
    }
    // stage W: wr[tap][ci][co], 16ci x 9tap x 64co = 2304 float4
    #pragma unroll
    for (int q=0;q<9;q++){
      int idx4 = tid + q*256;
      int c4 = idx4 & 15;
      int row = idx4 >> 4;   // k*9 + t
      int k = row / 9, t = row % 9;
      float4 wv = *(const float4*)(wr + ((size_t)t*256 + k0 + k)*256 + co0 + c4*4);
      *(float4*)&Wsm[k][t][c4*4] = wv;
    }
    __syncthreads();
    #pragma unroll 2
    for (int k=0;k<16;k++){
      #pragma unroll
      for (int ky=0;ky<3;ky++){
        float4 xa = *(const float4*)&Xs[k][ky][tx*4];
        float4 xb = *(const float4*)&Xs[k][ky][tx*4+4];
        float xwin[8] = {xa.x,xa.y,xa.z,xa.w,xb.x,xb.y,xb.z,xb.w};
        #pragma unroll
        for (int kx=0;kx<3;kx++){
          float4 av = *(const float4*)&Wsm[k][ky*3+kx][ty*4];
          float aarr[4] = {av.x, av.y, av.z, av.w};
          #pragma unroll
          for (int i=0;i<4;i++)
            #pragma unroll
            for (int j=0;j<4;j++)
              acc[i][j] = fmaf(aarr[i], xwin[kx+j], acc[i][j]);
        }
      }
    }
    __syncthreads();
  }
  // epilogue: fused bias + BN + ReLU
  int oslot = oslot_begin + blockIdx.y;
  int xbase = x0 + tx*4;
  #pragma unroll
  for (int i=0;i<4;i++){
    int co = co0 + ty*4 + i;
    float s  = gam[co] * rsqrtf(var[co] + EPSV);
    float sh = (bias[co] - mu[co]) * s + bet[co];
    float vv[4];
    #pragma unroll
    for (int j=0;j<4;j++) vv[j] = fmaxf(fmaf(acc[i][j], s, sh), 0.f);
    float* dst = outb + (((size_t)(b*256+co))*RBout + oslot)*W + xbase;
    if (full) *(float4*)dst = make_float4(vv[0],vv[1],vv[2],vv[3]);
    else {
      #pragma unroll
      for (int j=0;j<4;j++) if (xbase+j < W) dst[j] = vv[j];
    }
  }
}

// ---------------- pred: 1x1 conv (256->45) + activations + sectioned scatter ----------------
__global__ __launch_bounds__(256) void k_pred(
    const float* __restrict__ inb, const float* __restrict__ wpT,
    const float* __restrict__ bp, float* __restrict__ outl,
    int H, int W, int y_begin, int RBin)
{
  __shared__ __align__(16) float Xs[16][64];
  __shared__ float Wsm[16][48];
  int tid = threadIdx.x, tx = tid & 15, ty = tid >> 4;
  int x0 = blockIdx.x * 64;
  int y = y_begin + blockIdx.y;
  int b = blockIdx.z;
  int slot = blockIdx.y;            // conv2 wrote rows [r0,r1) at slots [0,Rc)
  bool full = (x0 + 64 <= W);
  const float* inbb = inb + (size_t)(b*256)*RBin*W + (size_t)slot*W;
  float acc[3][4] = {};
  int sk = tid >> 4, sx = (tid & 15)*4;

  for (int k0=0;k0<256;k0+=16){
    float4 xv = make_float4(0.f,0.f,0.f,0.f);
    {
      const float* src = inbb + (size_t)(k0+sk)*RBin*W + x0 + sx;
      if (full) xv = *(const float4*)src;
      else {
        float t4[4]={0.f,0.f,0.f,0.f};
        int xg = x0 + sx;
        #pragma unroll
        for (int m=0;m<4;m++) if (xg+m < W) t4[m] = src[m];
        xv = make_float4(t4[0],t4[1],t4[2],t4[3]);
      }
    }
    *(float4*)&Xs[sk][sx] = xv;
    for (int idx=tid; idx<16*48; idx+=256){
      int k = idx / 48, c = idx % 48;
      Wsm[k][c] = (c < 45) ? wpT[(size_t)(k0+k)*45 + c] : 0.f;
    }
    __syncthreads();
    #pragma unroll
    for (int k=0;k<16;k++){
      float4 bv = *(const float4*)&Xs[k][tx*4];
      float barr[4] = {bv.x,bv.y,bv.z,bv.w};
      float a0 = Wsm[k][ty], a1 = Wsm[k][ty+16], a2 = Wsm[k][ty+32];
      #pragma unroll
      for (int j=0;j<4;j++){
        acc[0][j] = fmaf(a0, barr[j], acc[0][j]);
        acc[1][j] = fmaf(a1, barr[j], acc[1][j]);
        acc[2][j] = fmaf(a2, barr[j], acc[2][j]);
      }
    }
    __syncthreads();
  }

  size_t S = (size_t)H * W;
  int xbase = x0 + tx*4;
  #pragma unroll
  for (int i=0;i<3;i++){
    int co = ty + 16*i;
    if (co < 45){
      float bs = bp[co];
      int a_idx = co / 15, c = co % 15;
      int cum, c0, n;
      if (c < 4)       { cum = 0;  c0 = 0;  n = 4; }
      else if (c == 4) { cum = 4;  c0 = 4;  n = 1; }
      else if (c < 10) { cum = 5;  c0 = 5;  n = 5; }
      else if (c < 14) { cum = 10; c0 = 10; n = 4; }
      else             { cum = 14; c0 = 14; n = 1; }
      size_t chan = ((size_t)(12*cum) + (size_t)((b*3 + a_idx)*n + (c - c0))) * S;
      float* dst = outl + chan + (size_t)y*W + xbase;
      float vv[4];
      #pragma unroll
      for (int j=0;j<4;j++){
        float val = acc[i][j] + bs;
        if (c == 4)       val = 1.f / (1.f + expf(-val));
        else if (c == 14) val = (val > 20.f ? val : log1pf(expf(val))) + 1.f;
        vv[j] = val;
      }
      if (full) *(float4*)dst = make_float4(vv[0],vv[1],vv[2],vv[3]);
      else {
        #pragma unroll
        for (int j=0;j<4;j++) if (xbase+j < W) dst[j] = vv[j];
      }
    }
  }
}

// ---------------- host ----------------
extern "C" void kernel_launch(void* const* d_in, const int* in_sizes, int n_in,
                              void* d_out, int out_size, void* d_ws, size_t ws_size,
                              hipStream_t stream)
{
  static const int Hs[4] = {192,96,48,24};
  static const int Wd[4] = {320,160,80,40};
  const float* feat[4] = {(const float*)d_in[0],(const float*)d_in[1],
                          (const float*)d_in[2],(const float*)d_in[3]};
  const float* adapt_w = (const float*)d_in[4];
  const float* adapt_b = (const float*)d_in[5];
  const float* w1 = (const float*)d_in[6];  const float* b1 = (const float*)d_in[7];
  const float* g1 = (const float*)d_in[8];  const float* be1= (const float*)d_in[9];
  const float* m1 = (const float*)d_in[10]; const float* v1 = (const float*)d_in[11];
  const float* w2 = (const float*)d_in[12]; const float* b2 = (const float*)d_in[13];
  const float* g2 = (const float*)d_in[14]; const float* be2= (const float*)d_in[15];
  const float* m2 = (const float*)d_in[16]; const float* v2 = (const float*)d_in[17];
  const float* wp = (const float*)d_in[18]; const float* bp = (const float*)d_in[19];
  float* out = (float*)d_out;
  float* ws  = (float*)d_ws;

  size_t off = 0;
  float* wTa = ws;        off += (size_t)4*256*256;
  float* wr1 = ws + off;  off += (size_t)4*9*256*256;
  float* wr2 = ws + off;  off += (size_t)4*9*256*256;
  float* wpT = ws + off;  off += (size_t)4*256*45;
  float* bufbase = ws + off;
  size_t avail = (ws_size/4 > off) ? (ws_size/4 - off) : 0;

  k_repackT<<<dim3((4*256*256   + 255)/256), dim3(256), 0, stream>>>(adapt_w, wTa);
  k_repack3<<<dim3((4*9*256*256 + 255)/256), dim3(256), 0, stream>>>(w1, wr1);
  k_repack3<<<dim3((4*9*256*256 + 255)/256), dim3(256), 0, stream>>>(w2, wr2);
  k_repackP<<<dim3((4*256*45    + 255)/256), dim3(256), 0, stream>>>(wp, wpT);

  size_t out_off = 0;
  for (int l=0;l<4;l++){
    int H = Hs[l], W = Wd[l];
    size_t S = (size_t)H*W;
    // rows of both ping-pong buffers that fit: per buffered row B*C*W = 1024*W floats
    long cap = (long)(avail / ((size_t)1024*W));
    long Rl  = (cap - 6) / 2;
    int R = (int)(Rl < 1 ? 1 : (Rl > H ? (long)H : Rl));
    int RB0 = R + 4, RB1 = R + 2;
    float* buf0 = bufbase;
    float* buf1 = bufbase + (size_t)1024*RB0*W;
    int nPxT = (W + 63) / 64;

    for (int r0 = 0; r0 < H; r0 += R){
      int r1 = (r0 + R < H) ? (r0 + R) : H;
      int Rc = r1 - r0;
      // adapt: rows [r0-2, r1+2) clipped; buf0 slot = y - (r0-2)
      int ya0 = (r0-2 < 0) ? 0 : r0-2;
      int ya1 = (r1+2 > H) ? H : r1+2;
      k_adapt<<<dim3(nPxT*4, ya1-ya0, 4), dim3(256), 0, stream>>>(
          feat[l], wTa + (size_t)l*65536, adapt_b + l*256, buf0,
          H, W, ya0, ya0 - (r0-2), RB0);
      // conv1: rows [r0-1, r1+1) clipped; reads buf0, writes buf1 slot = y-(r0-1)
      int yb0 = (r0-1 < 0) ? 0 : r0-1;
      int yb1 = (r1+1 > H) ? H : r1+1;
      k_conv3<<<dim3(nPxT*4, yb1-yb0, 4), dim3(256), 0, stream>>>(
          buf0, wr1 + (size_t)l*9*65536,
          b1 + l*256, g1 + l*256, be1 + l*256, m1 + l*256, v1 + l*256,
          buf1, H, W, yb0, (yb0-1) - (r0-2), RB0, yb0 - (r0-1), RB1);
      // conv2: rows [r0, r1); reads buf1, writes buf0 slots [0,Rc)
      k_conv3<<<dim3(nPxT*4, Rc, 4), dim3(256), 0, stream>>>(
          buf1, wr2 + (size_t)l*9*65536,
          b2 + l*256, g2 + l*256, be2 + l*256, m2 + l*256, v2 + l*256,
          buf0, H, W, r0, 0, RB1, 0, RB0);
      // pred: rows [r0, r1); reads buf0 slots [0,Rc), writes sectioned output
      k_pred<<<dim3(nPxT, Rc, 4), dim3(256), 0, stream>>>(
          buf0, wpT + (size_t)l*256*45, bp + l*45, out + out_off,
          H, W, r0, RB0);
    }
    out_off += (size_t)4*45*S;
  }
}

// Round 2
// 1680.599 us; speedup vs baseline: 8.8365x; 8.8365x over previous
//
#include <hip/hip_runtime.h>
#include <math.h>

typedef __attribute__((ext_vector_type(8))) short bf16x8;
typedef __attribute__((ext_vector_type(4))) float f32x4;
typedef __attribute__((ext_vector_type(4))) unsigned short us4;

__device__ inline unsigned short f2bf(float f){
  unsigned u = __float_as_uint(f);
  u += 0x7fff + ((u>>16)&1);
  return (unsigned short)(u>>16);
}

// ---------- feat NCHW fp32 -> featT NHWC bf16 (row chunk) ----------
__global__ __launch_bounds__(256) void k_trans(const float* __restrict__ feat,
    unsigned short* __restrict__ ft, int H, int W, int y_begin, int slot_base, int RBf)
{
  int t = threadIdx.x;
  int lane = t & 63, wv = t >> 6;
  int x = blockIdx.x*64 + lane;
  int y = y_begin + blockIdx.y;
  int b = blockIdx.z;
  int slot = slot_base + blockIdx.y;
  if (x >= W) return;
  const float* fb = feat + ((size_t)(b*256)*H + y)*W + x;
  unsigned short* dst = ft + (((size_t)b*RBf + slot)*W + x)*256;
  #pragma unroll 4
  for (int i=0;i<16;i++){
    int c0 = wv*4 + i*16;
    float v0 = fb[(size_t)(c0+0)*H*W];
    float v1 = fb[(size_t)(c0+1)*H*W];
    float v2 = fb[(size_t)(c0+2)*H*W];
    float v3 = fb[(size_t)(c0+3)*H*W];
    us4 o = { f2bf(v0), f2bf(v1), f2bf(v2), f2bf(v3) };
    *(us4*)(dst + c0) = o;
  }
}

// ---------- weight repacks to MFMA fragment-linear order ----------
// conv 3x3: w [L][co][ci][9] fp32 * BN scale -> [l][cb16][kc8][tap9][lane64][8] bf16
__global__ __launch_bounds__(256) void k_repack_conv(const float* __restrict__ w,
    const float* __restrict__ g, const float* __restrict__ v,
    unsigned short* __restrict__ wf)
{
  int t = blockIdx.x*256 + threadIdx.x;
  if (t >= 4*256*256) return;
  int ci = t & 255, co = (t>>8) & 255, l = t>>16;
  float s = g[l*256+co] * rsqrtf(v[l*256+co] + 1e-5f);
  const float* wp = w + (size_t)t*9;
  int cb = co>>4, kc = ci>>5;
  int lane = ((ci>>3)&3)*16 + (co&15);
  int e = ci&7;
  size_t base = (((size_t)(l*16+cb)*8 + kc)*9)*512 + (size_t)lane*8 + e;
  #pragma unroll
  for (int tap=0;tap<9;tap++)
    wf[base + (size_t)tap*512] = f2bf(wp[tap]*s);
}

// adapt 1x1: [L][co][ci] -> [l][cb16][kc8][lane64][8]
__global__ __launch_bounds__(256) void k_repack_adapt(const float* __restrict__ w,
    unsigned short* __restrict__ wf)
{
  int t = blockIdx.x*256 + threadIdx.x;
  if (t >= 4*256*32) return;
  int o = t & 31, co = (t>>5)&255, l = t>>13;
  int ci0 = o*8;
  const float* wp = w + ((size_t)(l*256+co)*256 + ci0);
  int cb = co>>4, kc = o>>2, lane = (o&3)*16 + (co&15);
  unsigned short* dst = wf + (((size_t)(l*16+cb)*8 + kc)*64 + lane)*8;
  unsigned short tmp[8];
  #pragma unroll
  for (int e=0;e<8;e++) tmp[e] = f2bf(wp[e]);
  *(us4*)dst = *(us4*)tmp; *(us4*)(dst+4) = *(us4*)(tmp+4);
}

// pred 1x1 (45->pad48): [L][45][ci] -> [l][kc8][f3][lane64][8]
__global__ __launch_bounds__(192) void k_repack_pred(const float* __restrict__ w,
    unsigned short* __restrict__ wf)
{
  int t = blockIdx.x*192 + threadIdx.x;
  if (t >= 4*48*32) return;
  int o = t & 31, co = (t>>5)%48, l = t/1536;
  int ci0 = o*8, f = co>>4, kc = o>>2, lane = (o&3)*16 + (co&15);
  unsigned short* dst = wf + ((((size_t)l*8 + kc)*3 + f)*64 + lane)*8;
  #pragma unroll
  for (int e=0;e<8;e++){
    float val = (co<45) ? w[((size_t)(l*45+co)*256 + ci0 + e)] : 0.f;
    dst[e] = f2bf(val);
  }
}

// BN-folded bias: (b-m)*g*rsqrt(v+eps)+beta, [4][256]
__global__ __launch_bounds__(256) void k_bias(const float* __restrict__ b,
    const float* __restrict__ g, const float* __restrict__ be,
    const float* __restrict__ m, const float* __restrict__ v,
    float* __restrict__ out)
{
  int t = blockIdx.x*256 + threadIdx.x;
  if (t >= 1024) return;
  float s = g[t]*rsqrtf(v[t]+1e-5f);
  out[t] = (b[t]-m[t])*s + be[t];
}

// ---------- MFMA conv: NHWC bf16 -> NHWC bf16, 256ci -> 256co ----------
template<int TAPS, bool RELU>
__global__ __launch_bounds__(256) void k_conv_mfma(
    const unsigned short* __restrict__ in, const unsigned short* __restrict__ wf,
    const float* __restrict__ bias, unsigned short* __restrict__ outb,
    int H, int W, int y_begin, int in_row0, int RBin, int out_row0, int RBout)
{
  constexpr int KY  = (TAPS==9)?3:1;
  constexpr int PXV = (TAPS==9)?66:64;
  constexpr int PAD = (TAPS==9)?1:0;
  __shared__ __align__(16) unsigned short Xs[KY][68][40];
  int tid = threadIdx.x;
  int lane = tid & 63, w = tid >> 6;
  int l15 = lane & 15, g4 = lane >> 4;
  int x0 = blockIdx.x * 64;
  int y  = y_begin + blockIdx.y;
  int b  = blockIdx.z;

  f32x4 acc[4][4];
  #pragma unroll
  for (int i=0;i<4;i++)
    #pragma unroll
    for (int j=0;j<4;j++) acc[i][j] = (f32x4){0.f,0.f,0.f,0.f};

  const unsigned short* inb = in + (size_t)b*RBin*W*256;

  for (int kc=0;kc<8;kc++){
    for (int idx = tid; idx < KY*PXV*4; idx += 256){
      int ky, px, q;
      if (TAPS==9){ ky = idx/264; int r = idx - ky*264; px = r>>2; q = r&3; }
      else        { ky = 0; px = idx>>2; q = idx&3; }
      int yg = y + ky - PAD;
      int xg = x0 - PAD + px;
      us4 v0 = {0,0,0,0}, v1 = {0,0,0,0};
      if (yg >= 0 && yg < H && xg >= 0 && xg < W){
        int slot = yg - in_row0;
        const unsigned short* src = inb + ((size_t)slot*W + xg)*256 + kc*32 + q*8;
        v0 = *(const us4*)src; v1 = *(const us4*)(src+4);
      }
      unsigned short* d = &Xs[ky][px][q*8];
      *(us4*)d = v0; *(us4*)(d+4) = v1;
    }
    __syncthreads();
    #pragma unroll
    for (int tap=0;tap<TAPS;tap++){
      constexpr int dummy = 0; (void)dummy;
      int ky = (TAPS==9)? tap/3 : 0;
      int kx = (TAPS==9)? tap%3 : 0;
      bf16x8 Bf[4];
      #pragma unroll
      for (int pf=0;pf<4;pf++)
        Bf[pf] = *(const bf16x8*)&Xs[ky][pf*16 + l15 + kx][g4*8];
      bf16x8 Af[4];
      #pragma unroll
      for (int cf=0;cf<4;cf++){
        int cb = w*4 + cf;
        Af[cf] = *(const bf16x8*)(wf + ((((size_t)cb*8 + kc)*TAPS + tap)*64 + lane)*8);
      }
      #pragma unroll
      for (int cf=0;cf<4;cf++)
        #pragma unroll
        for (int pf=0;pf<4;pf++)
          acc[cf][pf] = __builtin_amdgcn_mfma_f32_16x16x32_bf16(Af[cf], Bf[pf], acc[cf][pf], 0,0,0);
    }
    __syncthreads();
  }

  int oslot = y - out_row0;
  #pragma unroll
  for (int cf=0;cf<4;cf++){
    int co0 = w*64 + cf*16 + g4*4;
    f32x4 bb = *(const f32x4*)(bias + co0);
    #pragma unroll
    for (int pf=0;pf<4;pf++){
      int px = x0 + pf*16 + l15;
      if (px < W){
        float v0 = acc[cf][pf][0] + bb[0];
        float v1 = acc[cf][pf][1] + bb[1];
        float v2 = acc[cf][pf][2] + bb[2];
        float v3 = acc[cf][pf][3] + bb[3];
        if (RELU){ v0=fmaxf(v0,0.f); v1=fmaxf(v1,0.f); v2=fmaxf(v2,0.f); v3=fmaxf(v3,0.f); }
        us4 o = { f2bf(v0), f2bf(v1), f2bf(v2), f2bf(v3) };
        *(us4*)(outb + (((size_t)(b*RBout + oslot)*W + px)*256 + co0)) = o;
      }
    }
  }
}

// ---------- pred MFMA: NHWC bf16 -> sectioned NCHW fp32 out ----------
__global__ __launch_bounds__(256) void k_pred_mfma(
    const unsigned short* __restrict__ in, const unsigned short* __restrict__ wfP,
    const float* __restrict__ bp, float* __restrict__ outl,
    int H, int W, int y_begin, int in_row0, int RBin)
{
  __shared__ __align__(16) unsigned short Xs[64][40];
  int tid = threadIdx.x;
  int lane = tid&63, w = tid>>6;
  int l15 = lane&15, g4 = lane>>4;
  int x0 = blockIdx.x*64;
  int y = y_begin + blockIdx.y;
  int b = blockIdx.z;
  int slot = y - in_row0;
  const unsigned short* inb = in + ((size_t)b*RBin + slot)*W*256;

  f32x4 acc[3];
  #pragma unroll
  for (int f=0;f<3;f++) acc[f] = (f32x4){0.f,0.f,0.f,0.f};

  for (int kc=0;kc<8;kc++){
    {
      int px = tid>>2, q = tid&3;
      int xg = x0+px;
      us4 v0={0,0,0,0}, v1={0,0,0,0};
      if (xg < W){
        const unsigned short* src = inb + (size_t)xg*256 + kc*32 + q*8;
        v0 = *(const us4*)src; v1 = *(const us4*)(src+4);
      }
      unsigned short* d = &Xs[px][q*8];
      *(us4*)d = v0; *(us4*)(d+4) = v1;
    }
    __syncthreads();
    bf16x8 Bf = *(const bf16x8*)&Xs[w*16 + l15][g4*8];
    #pragma unroll
    for (int f=0;f<3;f++){
      bf16x8 Af = *(const bf16x8*)(wfP + (((size_t)kc*3 + f)*64 + lane)*8);
      acc[f] = __builtin_amdgcn_mfma_f32_16x16x32_bf16(Af, Bf, acc[f], 0,0,0);
    }
    __syncthreads();
  }
  size_t S = (size_t)H*W;
  int px = x0 + w*16 + l15;
  if (px >= W) return;
  #pragma unroll
  for (int f=0;f<3;f++){
    #pragma unroll
    for (int r=0;r<4;r++){
      int co = f*16 + g4*4 + r;
      if (co < 45){
        float val = acc[f][r] + bp[co];
        int a_idx = co/15, c = co%15;
        int cum,c0,n;
        if (c<4)       {cum=0;c0=0;n=4;}
        else if (c==4) {cum=4;c0=4;n=1;}
        else if (c<10) {cum=5;c0=5;n=5;}
        else if (c<14) {cum=10;c0=10;n=4;}
        else           {cum=14;c0=14;n=1;}
        if (c==4) val = 1.f/(1.f+expf(-val));
        else if (c==14) val = (val>20.f? val : log1pf(expf(val))) + 1.f;
        size_t chan = ((size_t)(12*cum) + (size_t)((b*3+a_idx)*n + (c-c0)))*S;
        outl[chan + (size_t)y*W + px] = val;
      }
    }
  }
}

// ---------- host ----------
extern "C" void kernel_launch(void* const* d_in, const int* in_sizes, int n_in,
                              void* d_out, int out_size, void* d_ws, size_t ws_size,
                              hipStream_t stream)
{
  static const int Hs[4] = {192,96,48,24};
  static const int Wd[4] = {320,160,80,40};
  const float* feat[4] = {(const float*)d_in[0],(const float*)d_in[1],
                          (const float*)d_in[2],(const float*)d_in[3]};
  const float* adapt_w = (const float*)d_in[4];
  const float* adapt_b = (const float*)d_in[5];
  const float* w1 = (const float*)d_in[6];  const float* b1 = (const float*)d_in[7];
  const float* g1 = (const float*)d_in[8];  const float* be1= (const float*)d_in[9];
  const float* m1 = (const float*)d_in[10]; const float* v1 = (const float*)d_in[11];
  const float* w2 = (const float*)d_in[12]; const float* b2 = (const float*)d_in[13];
  const float* g2 = (const float*)d_in[14]; const float* be2= (const float*)d_in[15];
  const float* m2 = (const float*)d_in[16]; const float* v2 = (const float*)d_in[17];
  const float* wp = (const float*)d_in[18]; const float* bp = (const float*)d_in[19];
  float* out = (float*)d_out;

  char* base = (char*)d_ws;
  size_t off = 0;
  auto alloc = [&](size_t bytes)->char*{
    char* p = base + off; off = (off + bytes + 255) & ~(size_t)255; return p; };

  const size_t WF3_L = (size_t)16*8*9*512;   // elems per level
  const size_t WFA_L = (size_t)16*8*512;
  const size_t WFP_L = (size_t)8*3*512;
  unsigned short* wf1 = (unsigned short*)alloc(4*WF3_L*2);
  unsigned short* wf2 = (unsigned short*)alloc(4*WF3_L*2);
  unsigned short* wfA = (unsigned short*)alloc(4*WFA_L*2);
  unsigned short* wfP = (unsigned short*)alloc(4*WFP_L*2);
  float* biasc1 = (float*)alloc(1024*4);
  float* biasc2 = (float*)alloc(1024*4);
  char*  bufbase = base + off;
  size_t rem = (ws_size > off) ? (ws_size - off) : 0;

  k_repack_conv <<<dim3(1024), dim3(256), 0, stream>>>(w1, g1, v1, wf1);
  k_repack_conv <<<dim3(1024), dim3(256), 0, stream>>>(w2, g2, v2, wf2);
  k_repack_adapt<<<dim3(128),  dim3(256), 0, stream>>>(adapt_w, wfA);
  k_repack_pred <<<dim3(32),   dim3(192), 0, stream>>>(wp, wfP);
  k_bias<<<dim3(4), dim3(256), 0, stream>>>(b1, g1, be1, m1, v1, biasc1);
  k_bias<<<dim3(4), dim3(256), 0, stream>>>(b2, g2, be2, m2, v2, biasc2);

  size_t out_off = 0;
  for (int l=0;l<4;l++){
    int H = Hs[l], W = Wd[l];
    size_t S = (size_t)H*W;
    size_t bytesPerRow = (size_t)4*W*256*2;   // one buffered row (all batches), bf16
    long rowsAvail = (long)(rem / bytesPerRow);
    long Rl = (rowsAvail - 10) / 3;
    int R = (int)(Rl < 1 ? 1 : (Rl > H ? (long)H : Rl));
    int RBf = R + 4, RB1 = R + 2;
    unsigned short* featT = (unsigned short*)bufbase;          // also conv2 output
    unsigned short* buf0  = featT + (size_t)4*RBf*W*256;
    unsigned short* buf1  = buf0  + (size_t)4*RBf*W*256;
    int nPxT = (W + 63) / 64;

    for (int r0 = 0; r0 < H; r0 += R){
      int r1 = (r0 + R < H) ? (r0 + R) : H;
      int Rc = r1 - r0;
      int ya0 = (r0-2 < 0) ? 0 : r0-2;
      int ya1 = (r1+2 > H) ? H : r1+2;
      int yb0 = (r0-1 < 0) ? 0 : r0-1;
      int yb1 = (r1+1 > H) ? H : r1+1;

      k_trans<<<dim3(nPxT, ya1-ya0, 4), dim3(256), 0, stream>>>(
          feat[l], featT, H, W, ya0, ya0-(r0-2), RBf);

      k_conv_mfma<1,false><<<dim3(nPxT, ya1-ya0, 4), dim3(256), 0, stream>>>(
          featT, wfA + (size_t)l*WFA_L, adapt_b + l*256, buf0,
          H, W, ya0, r0-2, RBf, r0-2, RBf);

      k_conv_mfma<9,true><<<dim3(nPxT, yb1-yb0, 4), dim3(256), 0, stream>>>(
          buf0, wf1 + (size_t)l*WF3_L, biasc1 + l*256, buf1,
          H, W, yb0, r0-2, RBf, r0-1, RB1);

      k_conv_mfma<9,true><<<dim3(nPxT, Rc, 4), dim3(256), 0, stream>>>(
          buf1, wf2 + (size_t)l*WF3_L, biasc2 + l*256, featT,
          H, W, r0, r0-1, RB1, r0, RBf);

      k_pred_mfma<<<dim3(nPxT, Rc, 4), dim3(256), 0, stream>>>(
          featT, wfP + (size_t)l*WFP_L, bp + l*45, out + out_off,
          H, W, r0, r0, RBf);
    }
    out_off += (size_t)4*45*S;
  }
}